// Round 5
// baseline (283.390 us; speedup 1.0000x reference)
//
#include <hip/hip_runtime.h>
#include <hip/hip_bf16.h>
#include <math.h>

#define NB 256
#define SS 512
#define LL 128

typedef short bf16x8 __attribute__((ext_vector_type(8)));
typedef float f32x4 __attribute__((ext_vector_type(4)));

template <int P>
__device__ __forceinline__ float swzf(float x) {
    return __int_as_float(__builtin_amdgcn_ds_swizzle(__float_as_int(x), P));
}
__device__ __forceinline__ short f2bf(float f) {
    __hip_bfloat16 h = __float2bfloat16(f);
    short s;
    __builtin_memcpy(&s, &h, 2);
    return s;
}

// One block (128 thr = 2 waves) per batch; wave 0 = fwd chain, wave 1 = bwd.
// Barrier-free main loop (same-wave DS ops are in-order; each wave touches
// only its own LDS regions). Per round the critical path is:
//   publish u image (2 cvt + 2 ds_write_b16) -> 4 broadcast ds_read_b128 ->
//   32 MFMAs (8 N-tiles x 4 chained K-frags, all-rows-equal A trick) ->
//   8 fmul+cndmask.
// Everything else is pipelined OFF the path: features are bulk-staged to
// per-wave LDS double-buffers every 16 rounds (plain dwordx4 loads issued 16
// rounds ahead of their ds_write), the feature row + mask for round r+1 are
// read from LDS during round r, and exp(f) for round r+1 is computed during
// round r. exp(trans) fragments live in 128 VGPRs. Exact power-of-2 rescale
// every 8 rounds, wave-local. One final block barrier; dot + loss + one
// atomicAdd per batch.
__global__ __launch_bounds__(128, 1) void crf_kernel(
    const float* __restrict__ feats,    // (B,S,L)
    const float* __restrict__ start_t,  // (L)
    const float* __restrict__ end_t,    // (L)
    const float* __restrict__ trans,    // (L,L)
    const float* __restrict__ conf,     // (B)
    const int* __restrict__ mask,       // (B,S)
    const int* __restrict__ labels,     // (B,S)
    float* __restrict__ out)            // scalar, pre-zeroed
{
    const int b = blockIdx.x;
    const int tid = threadIdx.x;
    const int isB = tid >> 6;   // 0 = fwd wave, 1 = bwd wave
    const int l = tid & 63;
    const int l15 = l & 15;
    const int g = l >> 4;       // k-quad

    __shared__ __align__(16) short img[2][LL];       // u image per wave
    __shared__ __align__(16) float fS[2][2][16 * LL]; // per-wave feat dbuf, 32 KB
    __shared__ int lmk[2][256];                      // per-wave mask by round
    __shared__ float sv[2][LL];
    __shared__ float sc[4];

    const float* fb = feats + (size_t)b * SS * LL;
    const int* mk = mask + b * SS;

    // ---- per-wave mask-by-round staging (own region; no barrier needed) ----
#pragma unroll
    for (int q = 0; q < 4; ++q) {
        const int r = l + 64 * q;
        lmk[isB][r] = isB ? mk[511 - r] : ((r < 255) ? mk[r + 1] : 0);
    }

    // ---- exp(transition) B-fragments: Bf[kt][nt], 32 frags = 128 VGPRs ----
    bf16x8 Bf[4][8];
#pragma unroll
    for (int kt = 0; kt < 4; ++kt) {
#pragma unroll
        for (int nt = 0; nt < 8; ++nt) {
            const int n = 16 * nt + l15;
            bf16x8 fr;
#pragma unroll
            for (int j = 0; j < 8; ++j) {
                const int k = 32 * kt + 8 * g + j;
                const float v = isB ? trans[n * LL + k] : trans[k * LL + n];
                fr[j] = f2bf(__expf(v));
            }
            Bf[kt][nt] = fr;
        }
    }

    // ---- chain state ----
    float x[8];
#pragma unroll
    for (int nt = 0; nt < 8; ++nt) {
        const int n = 16 * nt + l15;
        x[nt] = isB ? __expf(end_t[n]) : __expf(start_t[n] + fb[n]);
    }
    int eacc = 0;

    // ---- feature chunk staging machinery (8 KB = 16 rounds per chunk) ----
    // chunk c covers rounds 16c..16c+15; fwd rows t=16c+1..16c+16 (ascending),
    // bwd rows t=511-16c..496-16c (slot s holds row 511-16c-s).
    float4 stg[8];
    auto issue_chunk = [&](int c) {
        c = c < 15 ? c : 15;
        const int mb = isB ? (496 - 16 * c) : (16 * c + 1);
        const float4* gp = (const float4*)(fb + (size_t)mb * LL);
#pragma unroll
        for (int q = 0; q < 8; ++q) stg[q] = gp[l + 64 * q];
    };
    auto write_chunk = [&](int c) {
        float* dst = fS[isB][c & 1];
#pragma unroll
        for (int q = 0; q < 8; ++q) {
            const int v = l + 64 * q;
            const int mrel = v >> 5;
            const int pos = v & 31;
            const int slot = isB ? (15 - mrel) : mrel;
            *(float4*)(dst + slot * LL + 4 * pos) = stg[q];
        }
    };

    issue_chunk(0);
    write_chunk(0);     // compiler inserts the vmcnt wait on stg use
    issue_chunk(1);     // in flight across the first 16 rounds

    // round-0 feature + mask prefetch (from buf 0) and exp
    float fn[8];
#pragma unroll
    for (int nt = 0; nt < 8; ++nt) fn[nt] = fS[isB][0][16 * nt + l15];
    int mt_n = lmk[isB][0];
    float ef[8];
#pragma unroll
    for (int nt = 0; nt < 8; ++nt) ef[nt] = __expf(fn[nt]);

    short* const myimg = img[isB];
    const f32x4 zf = {0.f, 0.f, 0.f, 0.f};

    for (int r = 0; r < 256; ++r) {
        if ((r & 15) == 0) {
            const int k = r >> 4;
            if (k < 15) {
                write_chunk(k + 1);   // data loaded 16 rounds ago
                issue_chunk(k + 2);   // in flight for the next 16 rounds
            }
        }
        const int mt = mt_n;
        float efc[8];
#pragma unroll
        for (int nt = 0; nt < 8; ++nt) efc[nt] = ef[nt];

        // ---- publish u image: quad g writes N-tiles 2g, 2g+1 ----
#pragma unroll
        for (int gg = 0; gg < 2; ++gg) {
            const int nt = 2 * g + gg;
            const float pub = isB ? efc[nt] * x[nt] : x[nt];
            myimg[16 * nt + l15] = f2bf(pub);
        }

        // ---- read A-frags (broadcast b128; same-wave in-order DS) ----
        bf16x8 a[4];
#pragma unroll
        for (int kt = 0; kt < 4; ++kt)
            __builtin_memcpy(&a[kt], &myimg[32 * kt + 8 * g], 16);

        // ---- prefetch round r+1 feature row + mask (off critical path) ----
        const int rn = (r < 255) ? (r + 1) : 255;
        const float* frow = &fS[isB][(rn >> 4) & 1][(rn & 15) * LL];
#pragma unroll
        for (int nt = 0; nt < 8; ++nt) fn[nt] = frow[16 * nt + l15];
        mt_n = lmk[isB][rn];

        // ---- 32 MFMAs: 8 independent accumulators, 4-deep K chains ----
        f32x4 c[8];
#pragma unroll
        for (int nt = 0; nt < 8; ++nt) {
            f32x4 cc = __builtin_amdgcn_mfma_f32_16x16x32_bf16(a[0], Bf[0][nt], zf, 0, 0, 0);
            cc = __builtin_amdgcn_mfma_f32_16x16x32_bf16(a[1], Bf[1][nt], cc, 0, 0, 0);
            cc = __builtin_amdgcn_mfma_f32_16x16x32_bf16(a[2], Bf[2][nt], cc, 0, 0, 0);
            cc = __builtin_amdgcn_mfma_f32_16x16x32_bf16(a[3], Bf[3][nt], cc, 0, 0, 0);
            c[nt] = cc;
        }

        // ---- next round's exp (off critical path) ----
#pragma unroll
        for (int nt = 0; nt < 8; ++nt) ef[nt] = __expf(fn[nt]);

        // ---- update: all C rows equal; c[nt][0] = (u*E)[16*nt + l15] ----
#pragma unroll
        for (int nt = 0; nt < 8; ++nt) {
            const float cand = isB ? c[nt][0] : efc[nt] * c[nt][0];
            x[nt] = mt ? cand : x[nt];
        }

        if ((r & 7) == 7) {
            // wave-local exact power-of-2 rescale (bitwise-identical lanes)
            float s = 0.f;
#pragma unroll
            for (int nt = 0; nt < 8; ++nt) s += x[nt];
            s += swzf<0x041F>(s);
            s += swzf<0x081F>(s);
            s += swzf<0x101F>(s);
            s += swzf<0x201F>(s);
            int ex;
            frexpf(s, &ex);
#pragma unroll
            for (int nt = 0; nt < 8; ++nt) x[nt] = ldexpf(x[nt], -ex);
            eacc += ex;
        }
    }

    // ---- export final vectors + exponents ----
    if (g == 0) {
#pragma unroll
        for (int nt = 0; nt < 8; ++nt) sv[isB][16 * nt + l15] = x[nt];
    }
    if (l == 0) sc[isB] = (float)eacc;

    // ---- numerator (gold path, fp32 exact) on the bwd wave ----
    if (isB) {
        const int* lb = labels + b * SS;
        float term = 0.f;
        int cnt = 0;
#pragma unroll
        for (int rr = 0; rr < 8; ++rr) {
            const int tt = l + 64 * rr;
            int lc = lb[tt];
            if ((unsigned)lc >= LL) lc = 0;
            const int m = mk[tt];
            cnt += (m != 0);
            if (tt == 0) {
                term += start_t[lc] + fb[lc];
            } else if (m) {
                int lp = lb[tt - 1];
                if ((unsigned)lp >= LL) lp = 0;
                term += trans[lp * LL + lc] + fb[(size_t)tt * LL + lc];
            }
        }
#pragma unroll
        for (int o = 1; o < 64; o <<= 1) {
            term += __shfl_xor(term, o);
            cnt += __shfl_xor(cnt, o);
        }
        if (l == 0) {
            int sl = cnt - 1;
            sl = sl < 0 ? 0 : (sl >= SS ? SS - 1 : sl);
            int lt = lb[sl];
            if ((unsigned)lt >= LL) lt = 0;
            sc[2] = term + end_t[lt];
        }
    }

    __syncthreads();  // the only block-wide barrier

    // ---- combine: Z = sum_i alpha_255[i] * beta_255[i] * 2^(eF+eB) ----
    if (tid < 64) {
        float p = sv[0][l] * sv[1][l] + sv[0][l + 64] * sv[1][l + 64];
#pragma unroll
        for (int o = 1; o < 64; o <<= 1) p += __shfl_xor(p, o);
        if (l == 0) {
            const float logZ =
                logf(p) + 0.69314718055994531f * (sc[0] + sc[1]);
            const float loss = (logZ - sc[2]) * conf[b] * (1.0f / NB);
            atomicAdd(out, loss);
        }
    }
}

extern "C" void kernel_launch(void* const* d_in, const int* in_sizes, int n_in,
                              void* d_out, int out_size, void* d_ws, size_t ws_size,
                              hipStream_t stream) {
    const float* feats  = (const float*)d_in[0];
    const float* startt = (const float*)d_in[1];
    const float* endt   = (const float*)d_in[2];
    const float* trans  = (const float*)d_in[3];
    const float* conf   = (const float*)d_in[4];
    const int*   mask   = (const int*)d_in[5];
    const int*   labels = (const int*)d_in[6];
    float* out = (float*)d_out;

    hipMemsetAsync(d_out, 0, sizeof(float), stream);
    hipLaunchKernelGGL(crf_kernel, dim3(NB), dim3(128), 0, stream,
                       feats, startt, endt, trans, conf, mask, labels, out);
}

// Round 6
// 258.644 us; speedup vs baseline: 1.0957x; 1.0957x over previous
//
#include <hip/hip_runtime.h>
#include <hip/hip_bf16.h>
#include <math.h>

#define NB 256
#define SS 512
#define LL 128

typedef short bf16x8 __attribute__((ext_vector_type(8)));
typedef float f32x4 __attribute__((ext_vector_type(4)));

template <int P>
__device__ __forceinline__ float swzf(float x) {
    return __int_as_float(__builtin_amdgcn_ds_swizzle(__float_as_int(x), P));
}
__device__ __forceinline__ short f2bf(float f) {
    __hip_bfloat16 h = __float2bfloat16(f);
    short s;
    __builtin_memcpy(&s, &h, 2);
    return s;
}

// One block = 64 threads = ONE wave = one chain (fwd or bwd) of one batch.
// grid = 512 (blocks 0..255 fwd, 256..511 bwd), 2 blocks/CU. No barriers
// anywhere: same-wave DS ops are in-order, block-private LDS.
// Round critical path: publish u image (2 cvt + 2 ds_write_b16) -> 4
// broadcast ds_read_b128 -> per N-tile two independent 2-deep MFMA chains
// + 1 v_add (only C reg0 is consumed) -> 8 cndmask.
// Off-path: feature loads (8 coalesced dwords/round into a statically
// indexed 4-round rotating register queue, issued 4 rounds ahead), exp(f)
// computed 1 round ahead, mask ds_read, exact power-of-2 rescale every 8
// rounds (wave-local, bitwise-identical across lanes).
__global__ __launch_bounds__(64, 1) void crf_chain_kernel(
    const float* __restrict__ feats,    // (B,S,L)
    const float* __restrict__ start_t,  // (L)
    const float* __restrict__ end_t,    // (L)
    const float* __restrict__ trans,    // (L,L)
    const int* __restrict__ mask,       // (B,S)
    const int* __restrict__ labels,     // (B,S)
    float* __restrict__ ws)             // av[32768] bv[32768] eF[256] eB[256] ln[256]
{
    const int bid = blockIdx.x;
    const int b = bid & 255;
    const int isB = bid >> 8;   // 0 = fwd chain, 1 = bwd chain
    const int l = threadIdx.x;  // 0..63
    const int l15 = l & 15;
    const int g = l >> 4;       // k-quad

    __shared__ __align__(16) short img[LL];  // u image, bf16
    __shared__ int lmk[256];                 // mask by ROUND index

    const float* fb = feats + (size_t)b * SS * LL;
    const int* mk = mask + b * SS;

    // ---- mask-by-round staging (single wave, in-order DS, no barrier) ----
#pragma unroll
    for (int q = 0; q < 4; ++q) {
        const int r = l + 64 * q;
        lmk[r] = isB ? mk[511 - r] : ((r < 255) ? mk[r + 1] : 0);
    }

    // ---- exp(transition) B-fragments: Bf[kt][nt], 32 frags ----
    // fwd: B[k][n] = exp(T[k][n]); bwd: exp(T[n][k]) (= T^T)
    bf16x8 Bf[4][8];
#pragma unroll
    for (int kt = 0; kt < 4; ++kt) {
#pragma unroll
        for (int nt = 0; nt < 8; ++nt) {
            const int n = 16 * nt + l15;
            bf16x8 fr;
#pragma unroll
            for (int j = 0; j < 8; ++j) {
                const int k = 32 * kt + 8 * g + j;
                const float v = isB ? trans[n * LL + k] : trans[k * LL + n];
                fr[j] = f2bf(__expf(v));
            }
            Bf[kt][nt] = fr;
        }
    }

    // ---- chain state: x[nt] = u[16*nt + l15], duplicated across g ----
    float x[8];
#pragma unroll
    for (int nt = 0; nt < 8; ++nt) {
        const int n = 16 * nt + l15;
        x[nt] = isB ? __expf(end_t[n]) : __expf(start_t[n] + fb[n]);
    }
    int eacc = 0;

    // round r -> timestep t: fwd t=r+1 (r=255 dummy), bwd t=511-r
    auto rowp = [&](int r) {
        const int t = isB ? (511 - r) : (r < 255 ? r + 1 : 255);
        return fb + (size_t)t * LL;
    };

    // ---- feature queue: slot h holds round (4k+h)'s 8 per-lane floats ----
    float fq[4][8];
#pragma unroll
    for (int h = 0; h < 4; ++h) {
        const float* rp = rowp(h);
#pragma unroll
        for (int nt = 0; nt < 8; ++nt) fq[h][nt] = rp[16 * nt + l15];
    }
    float ef[8], efn[8];
#pragma unroll
    for (int nt = 0; nt < 8; ++nt) ef[nt] = __expf(fq[0][nt]);
    int mt_c = lmk[0];

    const f32x4 zf = {0.f, 0.f, 0.f, 0.f};

    for (int it = 0; it < 64; ++it) {
#pragma unroll
        for (int h = 0; h < 4; ++h) {
            const int r = 4 * it + h;

            // ---- issue loads for round r+4 into slot h (data consumed) ----
            if (it < 63) {
                const float* rp = rowp(r + 4);
#pragma unroll
                for (int nt = 0; nt < 8; ++nt) fq[h][nt] = rp[16 * nt + l15];
            }

            // ---- publish u image: quad g writes N-tiles 2g, 2g+1 ----
#pragma unroll
            for (int gg = 0; gg < 2; ++gg) {
                const int nt = 2 * g + gg;
                const float pub = isB ? ef[nt] * x[nt] : x[nt];
                img[16 * nt + l15] = f2bf(pub);
            }

            // ---- read A-frags (broadcast b128, same-wave in-order DS) ----
            bf16x8 a[4];
#pragma unroll
            for (int kt = 0; kt < 4; ++kt)
                __builtin_memcpy(&a[kt], &img[32 * kt + 8 * g], 16);

            // ---- next round's exp + mask (off critical path) ----
            {
                const int hn = (h + 1) & 3;
#pragma unroll
                for (int nt = 0; nt < 8; ++nt) efn[nt] = __expf(fq[hn][nt]);
            }
            const int mt_n = lmk[(r < 255) ? (r + 1) : 255];

            // ---- MFMA: per N-tile, two independent 2-deep chains + add ----
            float cres[8];
#pragma unroll
            for (int nt = 0; nt < 8; ++nt) {
                f32x4 c1 = __builtin_amdgcn_mfma_f32_16x16x32_bf16(a[0], Bf[0][nt], zf, 0, 0, 0);
                f32x4 c2 = __builtin_amdgcn_mfma_f32_16x16x32_bf16(a[2], Bf[2][nt], zf, 0, 0, 0);
                c1 = __builtin_amdgcn_mfma_f32_16x16x32_bf16(a[1], Bf[1][nt], c1, 0, 0, 0);
                c2 = __builtin_amdgcn_mfma_f32_16x16x32_bf16(a[3], Bf[3][nt], c2, 0, 0, 0);
                cres[nt] = c1[0] + c2[0];
            }

            // ---- update (all C rows equal; cres = (u_pub*E)[16nt+l15]) ----
#pragma unroll
            for (int nt = 0; nt < 8; ++nt) {
                const float cand = isB ? cres[nt] : ef[nt] * cres[nt];
                x[nt] = mt_c ? cand : x[nt];
            }

            // rotate pipelined state
            mt_c = mt_n;
#pragma unroll
            for (int nt = 0; nt < 8; ++nt) ef[nt] = efn[nt];

            if ((r & 7) == 7) {
                // wave-local exact power-of-2 rescale (identical on lanes)
                float s = 0.f;
#pragma unroll
                for (int nt = 0; nt < 8; ++nt) s += x[nt];
                s += swzf<0x041F>(s);  // xor 1
                s += swzf<0x081F>(s);  // xor 2
                s += swzf<0x101F>(s);  // xor 4
                s += swzf<0x201F>(s);  // xor 8
                int ex;
                frexpf(s, &ex);
#pragma unroll
                for (int nt = 0; nt < 8; ++nt) x[nt] = ldexpf(x[nt], -ex);
                eacc += ex;
            }
        }
    }

    // ---- export final vector + exponent ----
    float* vout = ws + (isB ? NB * LL : 0) + b * LL;
    if (g == 0) {
#pragma unroll
        for (int nt = 0; nt < 8; ++nt) vout[16 * nt + l15] = x[nt];
    }
    if (l == 0) ws[2 * NB * LL + isB * NB + b] = (float)eacc;

    // ---- numerator (gold path, fp32 exact) on the bwd blocks ----
    if (isB) {
        const int* lb = labels + b * SS;
        float term = 0.f;
        int cnt = 0;
#pragma unroll
        for (int rr = 0; rr < 8; ++rr) {
            const int tt = l + 64 * rr;
            int lc = lb[tt];
            if ((unsigned)lc >= LL) lc = 0;
            const int m = mk[tt];
            cnt += (m != 0);
            if (tt == 0) {
                term += start_t[lc] + fb[lc];
            } else if (m) {
                int lp = lb[tt - 1];
                if ((unsigned)lp >= LL) lp = 0;
                term += trans[lp * LL + lc] + fb[(size_t)tt * LL + lc];
            }
        }
#pragma unroll
        for (int o = 1; o < 64; o <<= 1) {
            term += __shfl_xor(term, o);
            cnt += __shfl_xor(cnt, o);
        }
        if (l == 0) {
            int sl = cnt - 1;
            sl = sl < 0 ? 0 : (sl >= SS ? SS - 1 : sl);
            int lt = lb[sl];
            if ((unsigned)lt >= LL) lt = 0;
            ws[2 * NB * LL + 2 * NB + b] = term + end_t[lt];
        }
    }
}

// Combine: Z = sum_i alpha_255[i]*beta_255[i] * 2^(eF+eB); loss reduce.
__global__ __launch_bounds__(256) void crf_final_kernel(
    const float* __restrict__ ws, const float* __restrict__ conf,
    float* __restrict__ out)
{
    const int tid = threadIdx.x;  // = batch index
    const float* av = ws;
    const float* bv = ws + NB * LL;
    const float* eFa = ws + 2 * NB * LL;
    const float* eBa = eFa + NB;
    const float* ln = eBa + NB;

    const float4* a4 = (const float4*)(av + tid * LL);
    const float4* b4 = (const float4*)(bv + tid * LL);
    float dot = 0.f;
#pragma unroll 8
    for (int k = 0; k < 32; ++k) {
        float4 a = a4[k], bb = b4[k];
        dot += a.x * bb.x + a.y * bb.y + a.z * bb.z + a.w * bb.w;
    }
    float logZ = logf(dot) + 0.69314718055994531f * (eFa[tid] + eBa[tid]);
    float loss = (logZ - ln[tid]) * conf[tid] * (1.0f / NB);

#pragma unroll
    for (int o = 1; o < 64; o <<= 1) loss += __shfl_xor(loss, o);
    __shared__ float red[4];
    if ((tid & 63) == 0) red[tid >> 6] = loss;
    __syncthreads();
    if (tid == 0) out[0] = red[0] + red[1] + red[2] + red[3];
}

extern "C" void kernel_launch(void* const* d_in, const int* in_sizes, int n_in,
                              void* d_out, int out_size, void* d_ws, size_t ws_size,
                              hipStream_t stream) {
    const float* feats  = (const float*)d_in[0];
    const float* startt = (const float*)d_in[1];
    const float* endt   = (const float*)d_in[2];
    const float* trans  = (const float*)d_in[3];
    const float* conf   = (const float*)d_in[4];
    const int*   mask   = (const int*)d_in[5];
    const int*   labels = (const int*)d_in[6];
    float* out = (float*)d_out;
    float* ws = (float*)d_ws;  // 2*256*128 + 3*256 floats ~ 266 KB

    hipLaunchKernelGGL(crf_chain_kernel, dim3(2 * NB), dim3(64), 0, stream,
                       feats, startt, endt, trans, mask, labels, ws);
    hipLaunchKernelGGL(crf_final_kernel, dim3(1), dim3(256), 0, stream,
                       ws, conf, out);
}